// Round 9
// baseline (48.844 us; speedup 1.0000x reference)
//
#include <hip/hip_runtime.h>
#include <math.h>

#define B_ 2048
#define D_ 512
#define H_ 512
#define A_ 18
#define T_ 16
#define MTF 16
#define MAXTILESF 144

typedef __attribute__((ext_vector_type(8))) short short8;
typedef __attribute__((ext_vector_type(4))) float f32x4;

// ws layout:
//   [0..16384)      ints: [17..34) offsets[T+1] | [256..2304) order[B]  (fallback uses more)
//   PART_OFF 16K    float part[B][16][32]   (4 MB)
//   W2T_OFF  5M     bf16 w2t[T][32][512]    (512 KB, a=18..31 zeroed)
//   W1T_OFF  6M     bf16 w1t[T][H][D]       (8 MB)
#define PART_OFF 16384
#define W2T_OFF  (5 << 20)
#define W1T_OFF  (6 << 20)
#define WS_NEED  (14 << 20)

__device__ __forceinline__ unsigned short f2bf(float f) {
    union { float f; unsigned int u; } v; v.f = f;
    unsigned int u = v.u;
    return (unsigned short)((u + 0x7fffu + ((u >> 16) & 1u)) >> 16);
}

// ---- prep: [0,1024) W1 transpose->bf16; [1024,1040) W2T; 1040 sort ----
__global__ __launch_bounds__(256) void nk_prep(const float* __restrict__ W1,
                                               const float* __restrict__ W2,
                                               const int* __restrict__ task_id,
                                               unsigned short* __restrict__ w1t,
                                               unsigned short* __restrict__ w2t,
                                               int* __restrict__ wsi) {
    int bid = blockIdx.x;
    int tid = threadIdx.x;
    if (bid < 1024) {
        __shared__ float tile[64][65];
        int hx = bid & 7, dy = (bid >> 3) & 7, t = bid >> 6;
        int cx = tid & 63, ry = tid >> 6;
        const float* src = W1 + ((size_t)t * D_ + dy * 64) * H_ + hx * 64;
#pragma unroll
        for (int i = 0; i < 16; ++i) {
            int row = i * 4 + ry;
            tile[row][cx] = src[(size_t)row * H_ + cx];
        }
        __syncthreads();
        unsigned short* dst = w1t + ((size_t)t * H_ + hx * 64) * D_ + dy * 64;
        int c4 = tid & 15, hr0 = tid >> 4;
#pragma unroll
        for (int i = 0; i < 4; ++i) {
            int hr = hr0 + i * 16;
            unsigned short uu[4] = { f2bf(tile[c4 * 4 + 0][hr]), f2bf(tile[c4 * 4 + 1][hr]),
                                     f2bf(tile[c4 * 4 + 2][hr]), f2bf(tile[c4 * 4 + 3][hr]) };
            *(uint2*)(dst + (size_t)hr * D_ + c4 * 4) = *(const uint2*)uu;
        }
    } else if (bid < 1040) {
        // W2 [t][512][18] fp32 -> w2t [t][32][512] bf16 (a>=18 zero)
        int t = bid - 1024;
        const float* src = W2 + (size_t)t * H_ * A_;
        unsigned short* dst = w2t + (size_t)t * 32 * H_;
#pragma unroll
        for (int i = 0; i < 2; ++i) {
            int h = tid * 2 + i;
            float v[A_];
#pragma unroll
            for (int a = 0; a < A_; ++a) v[a] = src[(size_t)h * A_ + a];
#pragma unroll
            for (int a = 0; a < A_; ++a) dst[(size_t)a * H_ + h] = f2bf(v[a]);
#pragma unroll
            for (int a = A_; a < 32; ++a) dst[(size_t)a * H_ + h] = 0;
        }
    } else {
        __shared__ int cnt[T_], cur[T_], soff[T_];
        if (tid < T_) { cnt[tid] = 0; cur[tid] = 0; }
        __syncthreads();
        for (int b = tid; b < B_; b += 256) atomicAdd(&cnt[task_id[b]], 1);
        __syncthreads();
        if (tid == 0) {
            int off = 0;
            for (int t = 0; t < T_; ++t) {
                soff[t] = off; wsi[17 + t] = off;
                off += cnt[t];
            }
            wsi[17 + T_] = off;
        }
        __syncthreads();
        for (int b = tid; b < B_; b += 256) {
            int t = task_id[b];
            int pos = atomicAdd(&cur[t], 1);
            wsi[256 + soff[t] + pos] = b;
        }
    }
}

// ---- gemm: block = (task, 32-col chunk), XCD-pinned; loops 64-row m-chunks ----
// fc1 MFMA + relu + partial fc2 MFMA (K=32 over own cols) -> part[r][16][32]
__global__ __launch_bounds__(256, 2) void nk_gemm(
        const float* __restrict__ xs,
        const unsigned short* __restrict__ w1t,
        const unsigned short* __restrict__ w2t,
        const float* __restrict__ b1,
        float* __restrict__ part,
        const int* __restrict__ wsi) {
    __shared__ unsigned short x_lds[64][520];   // 66.6 KB
    __shared__ unsigned short h_lds[64][36];    // 4.5 KB
    __shared__ int sidx[64];

    int c = blockIdx.x;                  // XCD id
    int slot = blockIdx.y;               // 0..31
    int t = c + (slot >> 4) * 8;
    int cq = slot & 15;
    int c0 = cq * 32;

    int o = wsi[17 + t];
    int n = wsi[18 + t] - o;

    int tid = threadIdx.x, lane = tid & 63, w = tid >> 6;
    int r15 = lane & 15, kg = lane >> 4;

    const unsigned short* bp0 = w1t + (size_t)t * H_ * D_ + (size_t)(c0 + r15) * D_ + kg * 8;
    const unsigned short* bp1 = bp0 + (size_t)16 * D_;
    const unsigned short* wa0 = w2t + (size_t)t * 32 * H_ + (size_t)r15 * H_ + c0 + kg * 8;
    const unsigned short* wa1 = wa0 + (size_t)16 * H_;
    float bv0 = b1[t * H_ + c0 + r15];
    float bv1 = b1[t * H_ + c0 + 16 + r15];

    for (int mb = 0; mb * 64 < n; ++mb) {
        int rowbase = o + mb * 64;
        int rows = n - mb * 64; if (rows > 64) rows = 64;

        if (tid < 64) sidx[tid] = wsi[256 + rowbase + (tid < rows ? tid : rows - 1)];
        __syncthreads();

        // stage 64 xs rows fp32 -> bf16 LDS: 4 threads/row, 128 cols each
        {
            int row = tid >> 2, cb = (tid & 3) * 128;
            const float* src = xs + (size_t)sidx[row] * D_ + cb;
#pragma unroll
            for (int j = 0; j < 8; ++j) {
                float4 v0 = *(const float4*)(src + j * 16);
                float4 v1 = *(const float4*)(src + j * 16 + 4);
                float4 v2 = *(const float4*)(src + j * 16 + 8);
                float4 v3 = *(const float4*)(src + j * 16 + 12);
                unsigned short uu[16] = {
                    f2bf(v0.x), f2bf(v0.y), f2bf(v0.z), f2bf(v0.w),
                    f2bf(v1.x), f2bf(v1.y), f2bf(v1.z), f2bf(v1.w),
                    f2bf(v2.x), f2bf(v2.y), f2bf(v2.z), f2bf(v2.w),
                    f2bf(v3.x), f2bf(v3.y), f2bf(v3.z), f2bf(v3.w) };
                *(uint4*)&x_lds[row][cb + j * 16]     = *(const uint4*)&uu[0];
                *(uint4*)&x_lds[row][cb + j * 16 + 8] = *(const uint4*)&uu[8];
            }
        }
        __syncthreads();

        // fc1: wave w = m-tile w (rows w*16..w*16+15), cols c0..c0+31 (2 n-tiles)
        f32x4 acc0 = {0.f,0.f,0.f,0.f}, acc1 = {0.f,0.f,0.f,0.f};
#pragma unroll
        for (int ks = 0; ks < 16; ++ks) {
            short8 af = *(const short8*)&x_lds[w * 16 + r15][ks * 32 + kg * 8];
            short8 b0 = *(const short8*)(bp0 + ks * 32);
            short8 b1f = *(const short8*)(bp1 + ks * 32);
            acc0 = __builtin_amdgcn_mfma_f32_16x16x32_bf16(af, b0, acc0, 0, 0, 0);
            acc1 = __builtin_amdgcn_mfma_f32_16x16x32_bf16(af, b1f, acc1, 0, 0, 0);
        }

        // bias + relu -> h_lds (local rows 0..63, local cols 0..31)
#pragma unroll
        for (int j = 0; j < 4; ++j) {
            int row = w * 16 + kg * 4 + j;
            float v;
            v = acc0[j] + bv0; h_lds[row][r15]      = f2bf(v > 0.f ? v : 0.f);
            v = acc1[j] + bv1; h_lds[row][16 + r15] = f2bf(v > 0.f ? v : 0.f);
        }
        __syncthreads();

        // fc2 partial: wave w = m-tile w; K=32 (this block's cols); 2 a-tiles
        {
            short8 hf = *(const short8*)&h_lds[w * 16 + r15][kg * 8];
            short8 w2f0 = *(const short8*)wa0;
            short8 w2f1 = *(const short8*)wa1;
            f32x4 p0 = {0.f,0.f,0.f,0.f}, p1 = {0.f,0.f,0.f,0.f};
            p0 = __builtin_amdgcn_mfma_f32_16x16x32_bf16(hf, w2f0, p0, 0, 0, 0);
            p1 = __builtin_amdgcn_mfma_f32_16x16x32_bf16(hf, w2f1, p1, 0, 0, 0);
#pragma unroll
            for (int j = 0; j < 4; ++j) {
                int lrow = w * 16 + kg * 4 + j;
                if (lrow < rows) {
                    float* pp = part + ((size_t)(rowbase + lrow) * 16 + cq) * 32;
                    pp[r15] = p0[j];
                    pp[16 + r15] = p1[j];
                }
            }
        }
        __syncthreads();
    }
}

// ---- final: sum 16 partials + bias, softmax, write outputs ----
__global__ __launch_bounds__(256) void nk_final(const float* __restrict__ part,
                                                const float* __restrict__ b2,
                                                const int* __restrict__ action,
                                                float* __restrict__ out,
                                                const int* __restrict__ wsi) {
    int r = blockIdx.x * 256 + threadIdx.x;
    if (r >= B_) return;
    int t = 0;
#pragma unroll
    for (int i = 1; i < T_; ++i) t += (r >= wsi[17 + i]) ? 1 : 0;
    int b = wsi[256 + r];

    float logits[A_];
#pragma unroll
    for (int a = 0; a < A_; ++a) logits[a] = b2[t * A_ + a];
    const float* pr = part + (size_t)r * 16 * 32;
#pragma unroll
    for (int cq = 0; cq < 16; ++cq) {
        const float* pc = pr + cq * 32;
#pragma unroll
        for (int a4 = 0; a4 < 5; ++a4) {
            float4 v = *(const float4*)(pc + a4 * 4);
            if (a4 * 4 + 0 < A_) logits[a4 * 4 + 0] += v.x;
            if (a4 * 4 + 1 < A_) logits[a4 * 4 + 1] += v.y;
            if (a4 * 4 + 2 < A_) logits[a4 * 4 + 2] += v.z;
            if (a4 * 4 + 3 < A_) logits[a4 * 4 + 3] += v.w;
        }
    }
    float m = -1e30f;
#pragma unroll
    for (int a = 0; a < A_; ++a) m = fmaxf(m, logits[a]);
    float S = 0.f, sle = 0.f;
#pragma unroll
    for (int a = 0; a < A_; ++a) {
        float e = expf(logits[a] - m);
        S += e;
        sle += logits[a] * e;
    }
    float logZ = m + logf(S);
    int as = action[b];
    out[b] = (float)as;
    out[B_ + b] = logits[as] - logZ;
    out[2 * B_ + b] = logZ - sle / S;
}

// ---------------- fallback path (round-1, known-good) ----------------

__global__ void nk_init(int* wsi) { int i = threadIdx.x; if (i < 50) wsi[i] = 0; }

__global__ void nk_count(const int* task_id, int* wsi) {
    int b = blockIdx.x * blockDim.x + threadIdx.x;
    if (b < B_) atomicAdd(&wsi[1 + task_id[b]], 1);
}

__global__ void nk_plan(int* wsi) {
    int off = 0, tot = 0;
    for (int t = 0; t < T_; ++t) {
        wsi[17 + t] = off;
        int cnt = wsi[1 + t];
        int nt = (cnt + MTF - 1) / MTF;
        for (int k = 0; k < nt; ++k) wsi[50 + tot++] = (t << 16) | k;
        off += cnt;
    }
    wsi[17 + T_] = off;
    wsi[0] = tot;
}

__global__ void nk_scatter(const int* task_id, int* wsi) {
    int b = blockIdx.x * blockDim.x + threadIdx.x;
    if (b < B_) {
        int t = task_id[b];
        int pos = atomicAdd(&wsi[34 + t], 1);
        wsi[256 + wsi[17 + t] + pos] = b;
    }
}

__global__ __launch_bounds__(512) void nk_main(
        const float* __restrict__ xs, const float* __restrict__ W1,
        const float* __restrict__ b1, const float* __restrict__ W2,
        const float* __restrict__ b2, const int* __restrict__ task_id,
        const int* __restrict__ action, float* __restrict__ out,
        const int* __restrict__ wsi) {
    __shared__ float tile[MTF][D_];
    __shared__ int sidx[MTF];
    int bid = blockIdx.x;
    if (bid >= wsi[0]) return;
    int code = wsi[50 + bid];
    int t = code >> 16, kt = code & 0xffff;
    int off0 = wsi[17 + t], off1 = wsi[17 + t + 1];
    int base = off0 + kt * MTF;
    int rows = off1 - base; if (rows > MTF) rows = MTF;
    int tid = threadIdx.x;
    if (tid < MTF) sidx[tid] = (tid < rows) ? wsi[256 + base + tid] : -1;
    __syncthreads();
    for (int i = 0; i < MTF; ++i) {
        int b = sidx[i];
        tile[i][tid] = (b >= 0) ? xs[(size_t)b * D_ + tid] : 0.f;
    }
    __syncthreads();
    const float* w1p = W1 + (size_t)t * D_ * H_ + tid;
    float acc[MTF];
#pragma unroll
    for (int i = 0; i < MTF; ++i) acc[i] = 0.f;
    for (int d = 0; d < D_; d += 4) {
        float w0 = w1p[(size_t)(d + 0) * H_];
        float w1v = w1p[(size_t)(d + 1) * H_];
        float w2v = w1p[(size_t)(d + 2) * H_];
        float w3v = w1p[(size_t)(d + 3) * H_];
#pragma unroll
        for (int i = 0; i < MTF; ++i) {
            float4 x = *(const float4*)&tile[i][d];
            float a0 = fmaf(x.x, w0, acc[i]);
            a0 = fmaf(x.y, w1v, a0);
            a0 = fmaf(x.z, w2v, a0);
            acc[i] = fmaf(x.w, w3v, a0);
        }
    }
    __syncthreads();
    float b1v = b1[t * H_ + tid];
#pragma unroll
    for (int i = 0; i < MTF; ++i) {
        float h = acc[i] + b1v;
        tile[i][tid] = h > 0.f ? h : 0.f;
    }
    __syncthreads();
    int g = tid >> 5, l = tid & 31;
    float lg[A_];
#pragma unroll
    for (int a = 0; a < A_; ++a) lg[a] = 0.f;
    const float* w2base = W2 + (size_t)t * H_ * A_;
    for (int hh = l; hh < H_; hh += 32) {
        float hv = tile[g][hh];
        const float* wrow = w2base + (size_t)hh * A_;
#pragma unroll
        for (int a = 0; a < A_; ++a) lg[a] = fmaf(hv, wrow[a], lg[a]);
    }
#pragma unroll
    for (int a = 0; a < A_; ++a) {
        lg[a] += __shfl_down(lg[a], 16, 32);
        lg[a] += __shfl_down(lg[a], 8, 32);
        lg[a] += __shfl_down(lg[a], 4, 32);
        lg[a] += __shfl_down(lg[a], 2, 32);
        lg[a] += __shfl_down(lg[a], 1, 32);
    }
    if (l == 0 && g < rows) {
        int b = sidx[g];
        float logits[A_];
        float m = -1e30f;
#pragma unroll
        for (int a = 0; a < A_; ++a) {
            logits[a] = lg[a] + b2[t * A_ + a];
            m = fmaxf(m, logits[a]);
        }
        float S = 0.f, sle = 0.f;
#pragma unroll
        for (int a = 0; a < A_; ++a) {
            float e = expf(logits[a] - m);
            S += e;
            sle += logits[a] * e;
        }
        float logZ = m + logf(S);
        int as = action[b];
        out[b] = (float)as;
        out[B_ + b] = logits[as] - logZ;
        out[2 * B_ + b] = logZ - sle / S;
    }
}

extern "C" void kernel_launch(void* const* d_in, const int* in_sizes, int n_in,
                              void* d_out, int out_size, void* d_ws, size_t ws_size,
                              hipStream_t stream) {
    const float* xs = (const float*)d_in[0];
    const float* W1 = (const float*)d_in[1];
    const float* b1 = (const float*)d_in[2];
    const float* W2 = (const float*)d_in[3];
    const float* b2 = (const float*)d_in[4];
    const int* task_id = (const int*)d_in[5];
    const int* action = (const int*)d_in[6];
    float* out = (float*)d_out;

    if (ws_size >= WS_NEED) {
        unsigned char* wsb = (unsigned char*)d_ws;
        int* wsi = (int*)d_ws;
        float* part = (float*)(wsb + PART_OFF);
        unsigned short* w2t = (unsigned short*)(wsb + W2T_OFF);
        unsigned short* w1t = (unsigned short*)(wsb + W1T_OFF);

        nk_prep<<<1041, 256, 0, stream>>>(W1, W2, task_id, w1t, w2t, wsi);
        nk_gemm<<<dim3(8, 32), 256, 0, stream>>>(xs, w1t, w2t, b1, part, wsi);
        nk_final<<<(B_ + 255) / 256, 256, 0, stream>>>(part, b2, action, out, wsi);
    } else {
        int* wsi = (int*)d_ws;
        nk_init<<<1, 64, 0, stream>>>(wsi);
        nk_count<<<(B_ + 255) / 256, 256, 0, stream>>>(task_id, wsi);
        nk_plan<<<1, 1, 0, stream>>>(wsi);
        nk_scatter<<<(B_ + 255) / 256, 256, 0, stream>>>(task_id, wsi);
        nk_main<<<MAXTILESF, 512, 0, stream>>>(xs, W1, b1, W2, b2, task_id, action, out, wsi);
    }
}

// Round 10
// 32.044 us; speedup vs baseline: 1.5243x; 1.5243x over previous
//
#include <hip/hip_runtime.h>
#include <math.h>

#define B_ 2048
#define D_ 512
#define H_ 512
#define A_ 18
#define T_ 16
#define MTF 16
#define MAXTILESF 144
#define NSLOT 24

typedef __attribute__((ext_vector_type(8))) short short8;
typedef __attribute__((ext_vector_type(4))) float f32x4;

// ws layout:
//   [0..16384)    ints: [17..34) offsets[T+1] | [256..2304) order[B]  (fallback uses more)
//   W2T_OFF 3MB   bf16 w2t[T][32][512]   (512 KB, a=18..31 zeroed)
//   W1T_OFF 4MB   bf16 w1t[T][H][D]      (8 MB)
#define W2T_OFF  (3 << 20)
#define W1T_OFF  (4 << 20)
#define WS_NEED  (12 << 20)

__device__ __forceinline__ unsigned short f2bf(float f) {
    union { float f; unsigned int u; } v; v.f = f;
    unsigned int u = v.u;
    return (unsigned short)((u + 0x7fffu + ((u >> 16) & 1u)) >> 16);
}

// ---- prep: [0,1024) W1 transpose->bf16; [1024,1040) W2T; 1040 sort ----
__global__ __launch_bounds__(256) void nk_prep(const float* __restrict__ W1,
                                               const float* __restrict__ W2,
                                               const int* __restrict__ task_id,
                                               unsigned short* __restrict__ w1t,
                                               unsigned short* __restrict__ w2t,
                                               int* __restrict__ wsi) {
    int bid = blockIdx.x;
    int tid = threadIdx.x;
    if (bid < 1024) {
        __shared__ float tile[64][65];
        int hx = bid & 7, dy = (bid >> 3) & 7, t = bid >> 6;
        int cx = tid & 63, ry = tid >> 6;
        const float* src = W1 + ((size_t)t * D_ + dy * 64) * H_ + hx * 64;
#pragma unroll
        for (int i = 0; i < 16; ++i) {
            int row = i * 4 + ry;
            tile[row][cx] = src[(size_t)row * H_ + cx];
        }
        __syncthreads();
        unsigned short* dst = w1t + ((size_t)t * H_ + hx * 64) * D_ + dy * 64;
        int c4 = tid & 15, hr0 = tid >> 4;
#pragma unroll
        for (int i = 0; i < 4; ++i) {
            int hr = hr0 + i * 16;
            unsigned short uu[4] = { f2bf(tile[c4 * 4 + 0][hr]), f2bf(tile[c4 * 4 + 1][hr]),
                                     f2bf(tile[c4 * 4 + 2][hr]), f2bf(tile[c4 * 4 + 3][hr]) };
            *(uint2*)(dst + (size_t)hr * D_ + c4 * 4) = *(const uint2*)uu;
        }
    } else if (bid < 1040) {
        // W2 [t][512][18] fp32 -> w2t [t][32][512] bf16 (a>=18 zero)
        int t = bid - 1024;
        const float* src = W2 + (size_t)t * H_ * A_;
        unsigned short* dst = w2t + (size_t)t * 32 * H_;
#pragma unroll
        for (int i = 0; i < 2; ++i) {
            int h = tid * 2 + i;
            float v[A_];
#pragma unroll
            for (int a = 0; a < A_; ++a) v[a] = src[(size_t)h * A_ + a];
#pragma unroll
            for (int a = 0; a < A_; ++a) dst[(size_t)a * H_ + h] = f2bf(v[a]);
#pragma unroll
            for (int a = A_; a < 32; ++a) dst[(size_t)a * H_ + h] = 0;
        }
    } else {
        __shared__ int cnt[T_], cur[T_], soff[T_];
        if (tid < T_) { cnt[tid] = 0; cur[tid] = 0; }
        __syncthreads();
        for (int b = tid; b < B_; b += 256) atomicAdd(&cnt[task_id[b]], 1);
        __syncthreads();
        if (tid == 0) {
            int off = 0;
            for (int t = 0; t < T_; ++t) {
                soff[t] = off; wsi[17 + t] = off;
                off += cnt[t];
            }
            wsi[17 + T_] = off;
        }
        __syncthreads();
        for (int b = tid; b < B_; b += 256) {
            int t = task_id[b];
            int pos = atomicAdd(&cur[t], 1);
            wsi[256 + soff[t] + pos] = b;
        }
    }
}

// ---- fused, XCD-pinned: c = blockIdx.x handles tasks {c, c+8} ----
__global__ __launch_bounds__(512) void nk_fused(
        const float* __restrict__ xs,
        const unsigned short* __restrict__ w1t,
        const unsigned short* __restrict__ w2t,
        const float* __restrict__ b1, const float* __restrict__ b2,
        const int* __restrict__ action, float* __restrict__ out,
        const int* __restrict__ wsi) {
    __shared__ unsigned short x_lds[16][520];   // bf16 xs tile
    __shared__ unsigned short h_lds[16][520];   // bf16 h tile
    __shared__ float lg_lds[4][16][36];         // fc2 K-split partials
    __shared__ int sidx[16];

    int c = blockIdx.x;                  // XCD id (linear%8 == blockIdx.x)
    int tid = threadIdx.x, lane = tid & 63, w = tid >> 6;
    int r15 = lane & 15, kg = lane >> 4;

    int o0 = wsi[17 + c],     n0 = wsi[18 + c] - o0;      // task c
    int o1 = wsi[17 + c + 8], n1 = wsi[18 + c + 8] - o1;  // task c+8
    int nt0 = (n0 + 15) >> 4, nt1 = (n1 + 15) >> 4;
    int ntot = nt0 + nt1;

    for (int u = blockIdx.y; u < ntot; u += NSLOT) {
        int t, kt, off0, rT;
        if (u < nt0) { t = c; kt = u; off0 = o0; rT = n0; }
        else { t = c + 8; kt = u - nt0; off0 = o1; rT = n1; }
        int rowbase = off0 + kt * 16;
        int rows = rT - kt * 16; if (rows > 16) rows = 16;

        if (tid < 16) sidx[tid] = wsi[256 + rowbase + (tid < rows ? tid : rows - 1)];
        __syncthreads();

        // stage 16 xs rows fp32 -> bf16 LDS (thread: row=tid>>5, 16 cols)
        {
            int row = tid >> 5, col = (tid & 31) * 16;
            const float* src = xs + (size_t)sidx[row] * D_ + col;
            float4 v0 = *(const float4*)(src);
            float4 v1 = *(const float4*)(src + 4);
            float4 v2 = *(const float4*)(src + 8);
            float4 v3 = *(const float4*)(src + 12);
            unsigned short uu[16] = {
                f2bf(v0.x), f2bf(v0.y), f2bf(v0.z), f2bf(v0.w),
                f2bf(v1.x), f2bf(v1.y), f2bf(v1.z), f2bf(v1.w),
                f2bf(v2.x), f2bf(v2.y), f2bf(v2.z), f2bf(v2.w),
                f2bf(v3.x), f2bf(v3.y), f2bf(v3.z), f2bf(v3.w) };
            *(uint4*)&x_lds[row][col]     = *(const uint4*)&uu[0];
            *(uint4*)&x_lds[row][col + 8] = *(const uint4*)&uu[8];
        }
        __syncthreads();

        // ---- fc1: wave w covers cols w*64 .. w*64+63 (4 n-tiles), rows 0..15
        // explicit register double-buffer: prefetch ks+1 while MFMA'ing ks
        const unsigned short* bbase = w1t + (size_t)t * H_ * D_ + kg * 8;
        const unsigned short* bp0 = bbase + (size_t)(w * 64 + r15) * D_;
        const unsigned short* bp1 = bp0 + (size_t)16 * D_;
        const unsigned short* bp2 = bp0 + (size_t)32 * D_;
        const unsigned short* bp3 = bp0 + (size_t)48 * D_;

        f32x4 acc0 = {0.f,0.f,0.f,0.f}, acc1 = {0.f,0.f,0.f,0.f};
        f32x4 acc2 = {0.f,0.f,0.f,0.f}, acc3 = {0.f,0.f,0.f,0.f};

        short8 a_cur = *(const short8*)&x_lds[r15][kg * 8];
        short8 b0c = *(const short8*)(bp0);
        short8 b1c = *(const short8*)(bp1);
        short8 b2c = *(const short8*)(bp2);
        short8 b3c = *(const short8*)(bp3);
#pragma unroll
        for (int ks = 0; ks < 16; ++ks) {
            short8 a_nxt, b0n, b1n, b2n, b3n;
            if (ks < 15) {
                a_nxt = *(const short8*)&x_lds[r15][(ks + 1) * 32 + kg * 8];
                b0n = *(const short8*)(bp0 + (ks + 1) * 32);
                b1n = *(const short8*)(bp1 + (ks + 1) * 32);
                b2n = *(const short8*)(bp2 + (ks + 1) * 32);
                b3n = *(const short8*)(bp3 + (ks + 1) * 32);
            }
            acc0 = __builtin_amdgcn_mfma_f32_16x16x32_bf16(a_cur, b0c, acc0, 0, 0, 0);
            acc1 = __builtin_amdgcn_mfma_f32_16x16x32_bf16(a_cur, b1c, acc1, 0, 0, 0);
            acc2 = __builtin_amdgcn_mfma_f32_16x16x32_bf16(a_cur, b2c, acc2, 0, 0, 0);
            acc3 = __builtin_amdgcn_mfma_f32_16x16x32_bf16(a_cur, b3c, acc3, 0, 0, 0);
            if (ks < 15) {
                a_cur = a_nxt; b0c = b0n; b1c = b1n; b2c = b2n; b3c = b3n;
            }
        }

        int colb = w * 64 + r15;
        float bv0 = b1[t * H_ + colb];
        float bv1 = b1[t * H_ + colb + 16];
        float bv2 = b1[t * H_ + colb + 32];
        float bv3 = b1[t * H_ + colb + 48];
#pragma unroll
        for (int j = 0; j < 4; ++j) {
            int row = kg * 4 + j;
            float v;
            v = acc0[j] + bv0; h_lds[row][colb]      = f2bf(v > 0.f ? v : 0.f);
            v = acc1[j] + bv1; h_lds[row][colb + 16] = f2bf(v > 0.f ? v : 0.f);
            v = acc2[j] + bv2; h_lds[row][colb + 32] = f2bf(v > 0.f ? v : 0.f);
            v = acc3[j] + bv3; h_lds[row][colb + 48] = f2bf(v > 0.f ? v : 0.f);
        }
        __syncthreads();

        // ---- fc2: waves 0..3, K-split: wave w takes ks = w*4 .. w*4+3 (K=128)
        // each wave computes 16x32 partial (2 a-tiles) -> lg_lds[w]
        if (w < 4) {
            const unsigned short* wa0 = w2t + (size_t)t * 32 * H_
                                        + (size_t)r15 * H_ + kg * 8;
            const unsigned short* wa1 = wa0 + (size_t)16 * H_;
            f32x4 c0 = {0.f,0.f,0.f,0.f}, c1 = {0.f,0.f,0.f,0.f};
#pragma unroll
            for (int j = 0; j < 4; ++j) {
                int ks = w * 4 + j;
                short8 hf = *(const short8*)&h_lds[r15][ks * 32 + kg * 8];
                short8 w0 = *(const short8*)(wa0 + ks * 32);
                short8 w1f = *(const short8*)(wa1 + ks * 32);
                c0 = __builtin_amdgcn_mfma_f32_16x16x32_bf16(hf, w0, c0, 0, 0, 0);
                c1 = __builtin_amdgcn_mfma_f32_16x16x32_bf16(hf, w1f, c1, 0, 0, 0);
            }
#pragma unroll
            for (int j = 0; j < 4; ++j) {
                int row = kg * 4 + j;
                lg_lds[w][row][r15] = c0[j];
                lg_lds[w][row][16 + r15] = c1[j];
            }
        }
        __syncthreads();

        // ---- softmax + outputs: one thread per row; sum 4 K-partials + bias
        if (tid < rows) {
            int b = sidx[tid];
            float logits[A_];
            float m = -1e30f;
#pragma unroll
            for (int a = 0; a < A_; ++a) {
                float v = lg_lds[0][tid][a] + lg_lds[1][tid][a]
                        + lg_lds[2][tid][a] + lg_lds[3][tid][a] + b2[t * A_ + a];
                logits[a] = v;
                m = fmaxf(m, v);
            }
            float S = 0.f, sle = 0.f;
#pragma unroll
            for (int a = 0; a < A_; ++a) {
                float e = expf(logits[a] - m);
                S += e;
                sle += logits[a] * e;
            }
            float logZ = m + logf(S);
            int as = action[b];
            out[b] = (float)as;
            out[B_ + b] = logits[as] - logZ;
            out[2 * B_ + b] = logZ - sle / S;
        }
        __syncthreads();   // protect sidx/x_lds/lg_lds before next unit
    }
}

// ---------------- fallback path (round-1, known-good) ----------------

__global__ void nk_init(int* wsi) { int i = threadIdx.x; if (i < 50) wsi[i] = 0; }

__global__ void nk_count(const int* task_id, int* wsi) {
    int b = blockIdx.x * blockDim.x + threadIdx.x;
    if (b < B_) atomicAdd(&wsi[1 + task_id[b]], 1);
}

__global__ void nk_plan(int* wsi) {
    int off = 0, tot = 0;
    for (int t = 0; t < T_; ++t) {
        wsi[17 + t] = off;
        int cnt = wsi[1 + t];
        int nt = (cnt + MTF - 1) / MTF;
        for (int k = 0; k < nt; ++k) wsi[50 + tot++] = (t << 16) | k;
        off += cnt;
    }
    wsi[17 + T_] = off;
    wsi[0] = tot;
}

__global__ void nk_scatter(const int* task_id, int* wsi) {
    int b = blockIdx.x * blockDim.x + threadIdx.x;
    if (b < B_) {
        int t = task_id[b];
        int pos = atomicAdd(&wsi[34 + t], 1);
        wsi[256 + wsi[17 + t] + pos] = b;
    }
}

__global__ __launch_bounds__(512) void nk_main(
        const float* __restrict__ xs, const float* __restrict__ W1,
        const float* __restrict__ b1, const float* __restrict__ W2,
        const float* __restrict__ b2, const int* __restrict__ task_id,
        const int* __restrict__ action, float* __restrict__ out,
        const int* __restrict__ wsi) {
    __shared__ float tile[MTF][D_];
    __shared__ int sidx[MTF];
    int bid = blockIdx.x;
    if (bid >= wsi[0]) return;
    int code = wsi[50 + bid];
    int t = code >> 16, kt = code & 0xffff;
    int off0 = wsi[17 + t], off1 = wsi[17 + t + 1];
    int base = off0 + kt * MTF;
    int rows = off1 - base; if (rows > MTF) rows = MTF;
    int tid = threadIdx.x;
    if (tid < MTF) sidx[tid] = (tid < rows) ? wsi[256 + base + tid] : -1;
    __syncthreads();
    for (int i = 0; i < MTF; ++i) {
        int b = sidx[i];
        tile[i][tid] = (b >= 0) ? xs[(size_t)b * D_ + tid] : 0.f;
    }
    __syncthreads();
    const float* w1p = W1 + (size_t)t * D_ * H_ + tid;
    float acc[MTF];
#pragma unroll
    for (int i = 0; i < MTF; ++i) acc[i] = 0.f;
    for (int d = 0; d < D_; d += 4) {
        float w0 = w1p[(size_t)(d + 0) * H_];
        float w1v = w1p[(size_t)(d + 1) * H_];
        float w2v = w1p[(size_t)(d + 2) * H_];
        float w3v = w1p[(size_t)(d + 3) * H_];
#pragma unroll
        for (int i = 0; i < MTF; ++i) {
            float4 x = *(const float4*)&tile[i][d];
            float a0 = fmaf(x.x, w0, acc[i]);
            a0 = fmaf(x.y, w1v, a0);
            a0 = fmaf(x.z, w2v, a0);
            acc[i] = fmaf(x.w, w3v, a0);
        }
    }
    __syncthreads();
    float b1v = b1[t * H_ + tid];
#pragma unroll
    for (int i = 0; i < MTF; ++i) {
        float h = acc[i] + b1v;
        tile[i][tid] = h > 0.f ? h : 0.f;
    }
    __syncthreads();
    int g = tid >> 5, l = tid & 31;
    float lg[A_];
#pragma unroll
    for (int a = 0; a < A_; ++a) lg[a] = 0.f;
    const float* w2base = W2 + (size_t)t * H_ * A_;
    for (int hh = l; hh < H_; hh += 32) {
        float hv = tile[g][hh];
        const float* wrow = w2base + (size_t)hh * A_;
#pragma unroll
        for (int a = 0; a < A_; ++a) lg[a] = fmaf(hv, wrow[a], lg[a]);
    }
#pragma unroll
    for (int a = 0; a < A_; ++a) {
        lg[a] += __shfl_down(lg[a], 16, 32);
        lg[a] += __shfl_down(lg[a], 8, 32);
        lg[a] += __shfl_down(lg[a], 4, 32);
        lg[a] += __shfl_down(lg[a], 2, 32);
        lg[a] += __shfl_down(lg[a], 1, 32);
    }
    if (l == 0 && g < rows) {
        int b = sidx[g];
        float logits[A_];
        float m = -1e30f;
#pragma unroll
        for (int a = 0; a < A_; ++a) {
            logits[a] = lg[a] + b2[t * A_ + a];
            m = fmaxf(m, logits[a]);
        }
        float S = 0.f, sle = 0.f;
#pragma unroll
        for (int a = 0; a < A_; ++a) {
            float e = expf(logits[a] - m);
            S += e;
            sle += logits[a] * e;
        }
        float logZ = m + logf(S);
        int as = action[b];
        out[b] = (float)as;
        out[B_ + b] = logits[as] - logZ;
        out[2 * B_ + b] = logZ - sle / S;
    }
}

extern "C" void kernel_launch(void* const* d_in, const int* in_sizes, int n_in,
                              void* d_out, int out_size, void* d_ws, size_t ws_size,
                              hipStream_t stream) {
    const float* xs = (const float*)d_in[0];
    const float* W1 = (const float*)d_in[1];
    const float* b1 = (const float*)d_in[2];
    const float* W2 = (const float*)d_in[3];
    const float* b2 = (const float*)d_in[4];
    const int* task_id = (const int*)d_in[5];
    const int* action = (const int*)d_in[6];
    float* out = (float*)d_out;

    if (ws_size >= WS_NEED) {
        unsigned char* wsb = (unsigned char*)d_ws;
        int* wsi = (int*)d_ws;
        unsigned short* w2t = (unsigned short*)(wsb + W2T_OFF);
        unsigned short* w1t = (unsigned short*)(wsb + W1T_OFF);

        nk_prep<<<1041, 256, 0, stream>>>(W1, W2, task_id, w1t, w2t, wsi);
        nk_fused<<<dim3(8, NSLOT), 512, 0, stream>>>(xs, w1t, w2t, b1, b2,
                                                     action, out, wsi);
    } else {
        int* wsi = (int*)d_ws;
        nk_init<<<1, 64, 0, stream>>>(wsi);
        nk_count<<<(B_ + 255) / 256, 256, 0, stream>>>(task_id, wsi);
        nk_plan<<<1, 1, 0, stream>>>(wsi);
        nk_scatter<<<(B_ + 255) / 256, 256, 0, stream>>>(task_id, wsi);
        nk_main<<<MAXTILESF, 512, 0, stream>>>(xs, W1, b1, W2, b2, task_id, action, out, wsi);
    }
}